// Round 1
// baseline (136.978 us; speedup 1.0000x reference)
//
#include <hip/hip_runtime.h>
#include <hip/hip_bf16.h>

// FC_KANLayer: B=6, T=1024, D_IN=256, D_OUT=512, NUM_GRIDS=8
// FUNC_LIST = [rbf, bs, dog, base, rbf, bs]
// f32 in/out; GEMMs via bf16 MFMA.
// R13 = R12 + GEMM restructure: 128x128 tiles (m97 structure, 8 ds_read : 16 MFMA
// per wave-K-step), split-K removed (direct f32 epilogue), k3 eliminated.

typedef short short8 __attribute__((ext_vector_type(8)));
typedef float floatx4 __attribute__((ext_vector_type(4)));

using bf16 = __hip_bfloat16;

#define LOG2E 1.44269504088896340736f
// c = sqrt(0.5*log2(e)); exp(-0.5 x^2) = exp2(-(c x)^2)
#define DOG_C  0.84932180028801904f
#define DOG_IC 1.17741002251547466f   // 1/c

constexpr int Tn   = 1024;
constexpr int DIN  = 256;
constexpr int DOUT = 512;
constexpr int NG   = 8;
constexpr int KSP  = DIN * NG;            // 2048
constexpr float INV_DENOM = 7.0f / 3.0f;  // 1/DENOM, DENOM = 3/7

__device__ __forceinline__ unsigned int bf16bits(float v) {
    return (unsigned int)__builtin_bit_cast(unsigned short, __float2bfloat16(v));
}
__device__ __forceinline__ float frombits(unsigned int u) {
    return __builtin_bit_cast(float, u);
}

// ================= K1 ========================================================
// [0,1536): LN+basis wave-per-row | [1536,2112): f32->bf16 convert (x8 vec)
// [2112,2240): dog-param transpose-pack (pre-scaled by DOG_C), 32x32 tiles
__global__ __launch_bounds__(256) void k1_kernel(
        const float* __restrict__ X,
        const float* __restrict__ w,
        const float* __restrict__ b,
        const float* __restrict__ grid_rbf,
        const float* __restrict__ grid_bs,
        const float* __restrict__ sw,
        const float* __restrict__ bw,
        const float* __restrict__ sc,
        const float* __restrict__ tr,
        bf16* __restrict__ Amat,            // [4096][2048]
        bf16* __restrict__ Sm,              // [1024][256]
        float* __restrict__ Xn2,            // [1024][256]
        bf16* __restrict__ swb,             // [512][2048]
        bf16* __restrict__ bwb,             // [512][256]
        unsigned int* __restrict__ roT,     // [256][512] packed bf16 (c/s, -c*t/s)
        unsigned short* __restrict__ wnT) { // [256][512] bf16 (-bw/c)
    __shared__ float u1[32][33], u2[32][33];
    int tid = threadIdx.x, bid = blockIdx.x;

    if (bid >= 2112) {
        // ---- transpose-pack role (pre-scaled) ------------------------------
        int tb = bid - 2112;                  // 0..127
        int dout0 = (tb >> 3) * 32, din0 = (tb & 7) * 32;
        #pragma unroll
        for (int p = 0; p < 4; p++) {
            int idx = p * 256 + tid;
            int r = idx >> 5, c = idx & 31;
            float vs = sc[(dout0 + r) * DIN + din0 + c];
            float vt = tr[(dout0 + r) * DIN + din0 + c];
            float vb = bw[(dout0 + r) * DIN + din0 + c];
            float inv = DOG_C / vs;
            unsigned int packed = bf16bits(inv) | (bf16bits(-vt * inv) << 16);
            u1[r][c] = __builtin_bit_cast(float, packed);
            u2[r][c] = -vb * DOG_IC;
        }
        __syncthreads();
        #pragma unroll
        for (int p = 0; p < 4; p++) {
            int idx = p * 256 + tid;
            int c = idx >> 5, r = idx & 31;   // consecutive tid -> consecutive r
            roT[(din0 + c) * DOUT + dout0 + r] = __builtin_bit_cast(unsigned int, u1[r][c]);
            wnT[(din0 + c) * DOUT + dout0 + r] = (unsigned short)bf16bits(u2[r][c]);
        }
        return;
    }
    if (bid >= 1536) {
        // ---- convert role ---------------------------------------------------
        int e = ((bid - 1536) * 256 + tid) * 8;    // [0, 1179648)
        const float* src = (e < 1048576) ? (sw + e) : (bw + (e - 1048576));
        bf16* dst = (e < 1048576) ? (swb + e) : (bwb + (e - 1048576));
        float4 v0 = *(const float4*)src;
        float4 v1 = *(const float4*)(src + 4);
        short8 p;
        p[0] = __builtin_bit_cast(short, __float2bfloat16(v0.x));
        p[1] = __builtin_bit_cast(short, __float2bfloat16(v0.y));
        p[2] = __builtin_bit_cast(short, __float2bfloat16(v0.z));
        p[3] = __builtin_bit_cast(short, __float2bfloat16(v0.w));
        p[4] = __builtin_bit_cast(short, __float2bfloat16(v1.x));
        p[5] = __builtin_bit_cast(short, __float2bfloat16(v1.y));
        p[6] = __builtin_bit_cast(short, __float2bfloat16(v1.z));
        p[7] = __builtin_bit_cast(short, __float2bfloat16(v1.w));
        *(short8*)dst = p;
        return;
    }

    // ---- LN + basis role ----------------------------------------------------
    int wv = tid >> 6, lane = tid & 63;
    int row = bid * 4 + wv;              // b*1024 + t
    int batch = row >> 10, t = row & 1023;

    float x[4];
    #pragma unroll
    for (int j = 0; j < 4; j++) x[j] = X[(size_t)row * DIN + j * 64 + lane];
    float s = x[0] + x[1] + x[2] + x[3];
    float ss = x[0] * x[0] + x[1] * x[1] + x[2] * x[2] + x[3] * x[3];
    #pragma unroll
    for (int o = 1; o < 64; o <<= 1) {
        s  += __shfl_xor(s, o);
        ss += __shfl_xor(ss, o);
    }
    float mu = s * (1.0f / DIN);
    float rstd = rsqrtf(ss * (1.0f / DIN) - mu * mu + 1e-5f);

    float xn[4];
    #pragma unroll
    for (int j = 0; j < 4; j++) {
        int din = j * 64 + lane;
        xn[j] = (x[j] - mu) * rstd * w[din] + b[din];
    }

    if (batch == 2) {
        #pragma unroll
        for (int j = 0; j < 4; j++)
            Xn2[(size_t)t * DIN + j * 64 + lane] = xn[j];
    } else if (batch == 3) {
        #pragma unroll
        for (int j = 0; j < 4; j++) {
            float e = __builtin_amdgcn_exp2f(-xn[j] * LOG2E);
            float si = xn[j] * __builtin_amdgcn_rcpf(1.0f + e);
            Sm[(size_t)t * DIN + j * 64 + lane] = __float2bfloat16(si);
        }
    } else {
        int which = (batch == 0) ? 0 : (batch == 1) ? 1 : (batch == 4) ? 2 : 3;
        bool is_rbf = (batch == 0) || (batch == 4);
        #pragma unroll
        for (int j = 0; j < 4; j++) {
            float v = xn[j];
            float outv[NG];
            if (is_rbf) {
                #pragma unroll
                for (int g = 0; g < NG; g++) {
                    float d = (v - grid_rbf[g]) * INV_DENOM;
                    outv[g] = __builtin_amdgcn_exp2f(-d * d * LOG2E);
                }
            } else {
                float g[12];
                #pragma unroll
                for (int i = 0; i < 12; i++) g[i] = grid_bs[i];
                float ih = 1.0f / (g[1] - g[0]);
                float ihk[3] = {ih, ih * 0.5f, ih * (1.0f / 3.0f)};
                float bs_[11];
                #pragma unroll
                for (int i = 0; i < 11; i++)
                    bs_[i] = (v >= g[i] && v < g[i + 1]) ? 1.0f : 0.0f;
                #pragma unroll
                for (int k = 1; k <= 3; k++) {
                    float rk = ihk[k - 1];
                    #pragma unroll
                    for (int i = 0; i < 10; i++) {
                        if (i <= 10 - k) {
                            bs_[i] = (v - g[i]) * rk * bs_[i]
                                   + (g[i + k + 1] - v) * rk * bs_[i + 1];
                        }
                    }
                }
                #pragma unroll
                for (int gg = 0; gg < NG; gg++) outv[gg] = bs_[gg];
            }
            short8 pv;
            #pragma unroll
            for (int gg = 0; gg < NG; gg++)
                pv[gg] = __builtin_bit_cast(short, __float2bfloat16(outv[gg]));
            *(short8*)((short*)Amat + (size_t)(which * Tn + t) * KSP
                       + (size_t)(j * 64 + lane) * NG) = pv;
        }
    }
}

// ---------------- GEMM core: 128x128 tile, BK=32, dbuf LDS, XOR-swizzled -----
// 4 waves; each wave owns a 64x64 output quadrant (4x4 16x16 fragments).
// Per wave-K-step: 8 ds_read_b128 feed 16 MFMA (m97 ratio).
template <int KS>
__device__ __forceinline__ void gemm128(const short* __restrict__ A,
                                        const short* __restrict__ Bw,
                                        int row0, int col0, int iters,
                                        int tid, char* smem, floatx4 acc[4][4]) {
    short* ldsA = (short*)smem;             // [2][128][32] = 16 KiB
    short* ldsB = (short*)(smem + 16384);   // [2][128][32] = 16 KiB
    int wv = tid >> 6, lane = tid & 63;
    int r16 = lane >> 2, cs = lane & 3;
    // staging: wave wv covers rows [wv*32, wv*32+32), two issues of 16 rows.
    // LDS dest is linear (wave base + lane*16B); source pre-swizzled so that
    // physical chunk p of row r holds global chunk p ^ ((r>>1)&3).
    int sr0 = wv * 32 + r16, sr1 = sr0 + 16;
    int cg0 = cs ^ ((sr0 >> 1) & 3);
    int cg1 = cs ^ ((sr1 >> 1) & 3);
    const short* gA0 = A  + (size_t)(row0 + sr0) * KS + cg0 * 8;
    const short* gA1 = A  + (size_t)(row0 + sr1) * KS + cg1 * 8;
    const short* gB0 = Bw + (size_t)(col0 + sr0) * KS + cg0 * 8;
    const short* gB1 = Bw + (size_t)(col0 + sr1) * KS + cg1 * 8;

    int m = lane & 15, q = lane >> 4;
    int wr = wv >> 1, wc = wv & 1;
    int oA[4], oB[4];
    #pragma unroll
    for (int i = 0; i < 4; i++) {
        int ra = wr * 64 + i * 16 + m;
        int rb = wc * 64 + i * 16 + m;
        oA[i] = ra * 32 + (q ^ ((ra >> 1) & 3)) * 8;
        oB[i] = rb * 32 + (q ^ ((rb >> 1) & 3)) * 8;
    }

    auto issue = [&](int buf, int kof) {
        short* dA = ldsA + buf * 4096 + wv * 1024;
        short* dB = ldsB + buf * 4096 + wv * 1024;
        __builtin_amdgcn_global_load_lds(
            (const __attribute__((address_space(1))) void*)(gA0 + kof),
            (__attribute__((address_space(3))) void*)dA, 16, 0, 0);
        __builtin_amdgcn_global_load_lds(
            (const __attribute__((address_space(1))) void*)(gA1 + kof),
            (__attribute__((address_space(3))) void*)(dA + 512), 16, 0, 0);
        __builtin_amdgcn_global_load_lds(
            (const __attribute__((address_space(1))) void*)(gB0 + kof),
            (__attribute__((address_space(3))) void*)dB, 16, 0, 0);
        __builtin_amdgcn_global_load_lds(
            (const __attribute__((address_space(1))) void*)(gB1 + kof),
            (__attribute__((address_space(3))) void*)(dB + 512), 16, 0, 0);
    };

    issue(0, 0);
    for (int i = 0; i < iters; i++) {
        int cur = i & 1;
        __syncthreads();
        if (i + 1 < iters) issue(cur ^ 1, (i + 1) * 32);
        const short* bA = ldsA + cur * 4096;
        const short* bB = ldsB + cur * 4096;
        short8 a[4], b[4];
        #pragma unroll
        for (int r = 0; r < 4; r++) {
            a[r] = *(const short8*)(bA + oA[r]);
            b[r] = *(const short8*)(bB + oB[r]);
        }
        #pragma unroll
        for (int r = 0; r < 4; r++)
            #pragma unroll
            for (int c = 0; c < 4; c++)
                acc[r][c] = __builtin_amdgcn_mfma_f32_16x16x32_bf16(
                    a[r], b[c], acc[r][c], 0, 0, 0);
    }
}

// ================= K2: heterogeneous mega-kernel =============================
// [0,512):   DoG: block = 256 unique dout (dt=bid&1) x 4 t
// [512,640): spline GEMM 128x128, K=2048, direct f32 epilogue
// [640,672): base GEMM 128x128, K=256
__global__ __launch_bounds__(256) void k2_kernel(const bf16* __restrict__ Amat,
                                                 const bf16* __restrict__ SWb,
                                                 const bf16* __restrict__ Sm,
                                                 const bf16* __restrict__ BWb,
                                                 const float* __restrict__ Xn2,
                                                 const unsigned int* __restrict__ roT,
                                                 const unsigned short* __restrict__ wnT,
                                                 float* __restrict__ out) {
    __shared__ alignas(16) char smem[32768];
    int bid = blockIdx.x, tid = threadIdx.x;

    if (bid < 512) {
        // ---- DoG role: 256 dout x 4 t --------------------------------------
        int dt = bid & 1, t0 = (bid >> 1) * 4;
        float* xs_ = (float*)smem;          // [4][256] = 4 KiB
        *(float4*)&xs_[tid * 4] = *(const float4*)&Xn2[(size_t)t0 * DIN + tid * 4];
        __syncthreads();

        int dout = dt * 256 + tid;
        float acc[4] = {0.f, 0.f, 0.f, 0.f};
        const unsigned int*   rop = roT + dout;
        const unsigned short* wnp = wnT + dout;

        for (int d = 0; d < DIN; d += 8) {
            unsigned int ro[8]; unsigned short wn[8];
            #pragma unroll
            for (int k = 0; k < 8; k++) {
                ro[k] = rop[(d + k) * DOUT];
                wn[k] = wnp[(d + k) * DOUT];
            }
            #pragma unroll
            for (int g = 0; g < 2; g++) {
                float4 xv[4];
                #pragma unroll
                for (int j = 0; j < 4; j++)
                    xv[j] = *(const float4*)&xs_[j * DIN + d + g * 4];  // broadcast
                #pragma unroll
                for (int k = 0; k < 4; k++) {
                    int kk = g * 4 + k;
                    float r = frombits(ro[kk] << 16);
                    float o = frombits(ro[kk] & 0xFFFF0000u);
                    float w = frombits(((unsigned int)wn[kk]) << 16);
                    #pragma unroll
                    for (int j = 0; j < 4; j++) {
                        float xval = ((const float*)&xv[j])[k];
                        float z = fmaf(xval, r, o);
                        float e = __builtin_amdgcn_exp2f(-(z * z));
                        acc[j] = fmaf(z * e, w, acc[j]);
                    }
                }
            }
        }
        size_t base = (size_t)2 * Tn * DOUT + (size_t)t0 * DOUT + dout;
        #pragma unroll
        for (int j = 0; j < 4; j++) out[base + (size_t)j * DOUT] = acc[j];
    } else if (bid < 640) {
        // ---- spline GEMM role: 128x128, K=2048, f32 direct -----------------
        int idx = bid - 512;
        int mt = idx >> 2, nt = idx & 3;        // 32 x 4
        int row0 = mt * 128, col0 = nt * 128;
        floatx4 acc[4][4];
        #pragma unroll
        for (int r = 0; r < 4; r++)
            #pragma unroll
            for (int c = 0; c < 4; c++) acc[r][c] = (floatx4)(0.0f);
        gemm128<KSP>((const short*)Amat, (const short*)SWb,
                     row0, col0, 64, tid, smem, acc);
        int which = row0 >> 10;                  // block never crosses a 1024-row seam
        int batch = (which == 0) ? 0 : (which == 1) ? 1 : (which == 2) ? 4 : 5;
        int t0 = row0 & 1023;
        int wv = tid >> 6, lane = tid & 63;
        int m = lane & 15, q = lane >> 4;
        int wr = wv >> 1, wc = wv & 1;
        #pragma unroll
        for (int r = 0; r < 4; r++)
            #pragma unroll
            for (int c = 0; c < 4; c++)
                #pragma unroll
                for (int rr = 0; rr < 4; rr++) {
                    int t = t0 + wr * 64 + r * 16 + q * 4 + rr;
                    int col = col0 + wc * 64 + c * 16 + m;
                    out[((size_t)batch * Tn + t) * DOUT + col] = acc[r][c][rr];
                }
    } else {
        // ---- base GEMM role: 128x128, K=256 --------------------------------
        int idx = bid - 640;
        int mt = idx >> 2, nt = idx & 3;        // 8 x 4
        int row0 = mt * 128, col0 = nt * 128;
        floatx4 acc[4][4];
        #pragma unroll
        for (int r = 0; r < 4; r++)
            #pragma unroll
            for (int c = 0; c < 4; c++) acc[r][c] = (floatx4)(0.0f);
        gemm128<DIN>((const short*)Sm, (const short*)BWb,
                     row0, col0, 8, tid, smem, acc);
        int wv = tid >> 6, lane = tid & 63;
        int m = lane & 15, q = lane >> 4;
        int wr = wv >> 1, wc = wv & 1;
        #pragma unroll
        for (int r = 0; r < 4; r++)
            #pragma unroll
            for (int c = 0; c < 4; c++)
                #pragma unroll
                for (int rr = 0; rr < 4; rr++) {
                    int row = row0 + wr * 64 + r * 16 + q * 4 + rr;
                    int col = col0 + wc * 64 + c * 16 + m;
                    out[((size_t)3 * Tn + row) * DOUT + col] = acc[r][c][rr];
                }
    }
}

extern "C" void kernel_launch(void* const* d_in, const int* in_sizes, int n_in,
                              void* d_out, int out_size, void* d_ws, size_t ws_size,
                              hipStream_t stream) {
    const float* X        = (const float*)d_in[0];
    const float* ln_w     = (const float*)d_in[1];
    const float* ln_b     = (const float*)d_in[2];
    const float* base_w   = (const float*)d_in[3];
    const float* spline_w = (const float*)d_in[4];
    const float* scale    = (const float*)d_in[5];
    const float* transl   = (const float*)d_in[6];
    const float* grid_rbf = (const float*)d_in[7];
    const float* grid_bs  = (const float*)d_in[8];
    float* out = (float*)d_out;

    char* ws = (char*)d_ws;
    bf16*  Amat = (bf16*)ws;                                   // 16 MiB   [4096][2048]
    bf16*  SWb  = (bf16*)(ws + 16777216);                      // 2 MiB    [512][2048]
    bf16*  BWb  = (bf16*)(ws + 18874368);                      // 0.25 MiB [512][256]
    bf16*  Sm   = (bf16*)(ws + 19136512);                      // 0.5 MiB  [1024][256]
    float* Xn2  = (float*)(ws + 19660800);                     // 1 MiB    [1024][256]
    unsigned int*   roT = (unsigned int*)(ws + 20709376);      // 0.5 MiB  [256][512]
    unsigned short* wnT = (unsigned short*)(ws + 21233664);    // 0.25 MiB [256][512]

    k1_kernel<<<2240, 256, 0, stream>>>(X, ln_w, ln_b, grid_rbf, grid_bs,
                                        spline_w, base_w, scale, transl,
                                        Amat, Sm, Xn2, SWb, BWb, roT, wnT);
    k2_kernel<<<672, 256, 0, stream>>>(Amat, SWb, Sm, BWb, Xn2, roT, wnT, out);
}

// Round 2
// 128.268 us; speedup vs baseline: 1.0679x; 1.0679x over previous
//
#include <hip/hip_runtime.h>
#include <hip/hip_bf16.h>

// FC_KANLayer: B=6, T=1024, D_IN=256, D_OUT=512, NUM_GRIDS=8
// FUNC_LIST = [rbf, bs, dog, base, rbf, bs]
// f32 in/out; GEMMs via bf16 MFMA.
// R14 = R13 + (a) GEMM roles first in bid order so DoG co-resides with GEMM
// (MFMA/VALU pipe overlap), (b) 3-buffer LDS pipeline with counted
// s_waitcnt vmcnt(4) + raw s_barrier (never drain prefetch; m201 pattern).

typedef short short8 __attribute__((ext_vector_type(8)));
typedef float floatx4 __attribute__((ext_vector_type(4)));

using bf16 = __hip_bfloat16;

#define LOG2E 1.44269504088896340736f
// c = sqrt(0.5*log2(e)); exp(-0.5 x^2) = exp2(-(c x)^2)
#define DOG_C  0.84932180028801904f
#define DOG_IC 1.17741002251547466f   // 1/c

constexpr int Tn   = 1024;
constexpr int DIN  = 256;
constexpr int DOUT = 512;
constexpr int NG   = 8;
constexpr int KSP  = DIN * NG;            // 2048
constexpr float INV_DENOM = 7.0f / 3.0f;  // 1/DENOM, DENOM = 3/7

__device__ __forceinline__ unsigned int bf16bits(float v) {
    return (unsigned int)__builtin_bit_cast(unsigned short, __float2bfloat16(v));
}
__device__ __forceinline__ float frombits(unsigned int u) {
    return __builtin_bit_cast(float, u);
}

// ================= K1 ========================================================
// [0,1536): LN+basis wave-per-row | [1536,2112): f32->bf16 convert (x8 vec)
// [2112,2240): dog-param transpose-pack (pre-scaled by DOG_C), 32x32 tiles
__global__ __launch_bounds__(256) void k1_kernel(
        const float* __restrict__ X,
        const float* __restrict__ w,
        const float* __restrict__ b,
        const float* __restrict__ grid_rbf,
        const float* __restrict__ grid_bs,
        const float* __restrict__ sw,
        const float* __restrict__ bw,
        const float* __restrict__ sc,
        const float* __restrict__ tr,
        bf16* __restrict__ Amat,            // [4096][2048]
        bf16* __restrict__ Sm,              // [1024][256]
        float* __restrict__ Xn2,            // [1024][256]
        bf16* __restrict__ swb,             // [512][2048]
        bf16* __restrict__ bwb,             // [512][256]
        unsigned int* __restrict__ roT,     // [256][512] packed bf16 (c/s, -c*t/s)
        unsigned short* __restrict__ wnT) { // [256][512] bf16 (-bw/c)
    __shared__ float u1[32][33], u2[32][33];
    int tid = threadIdx.x, bid = blockIdx.x;

    if (bid >= 2112) {
        // ---- transpose-pack role (pre-scaled) ------------------------------
        int tb = bid - 2112;                  // 0..127
        int dout0 = (tb >> 3) * 32, din0 = (tb & 7) * 32;
        #pragma unroll
        for (int p = 0; p < 4; p++) {
            int idx = p * 256 + tid;
            int r = idx >> 5, c = idx & 31;
            float vs = sc[(dout0 + r) * DIN + din0 + c];
            float vt = tr[(dout0 + r) * DIN + din0 + c];
            float vb = bw[(dout0 + r) * DIN + din0 + c];
            float inv = DOG_C / vs;
            unsigned int packed = bf16bits(inv) | (bf16bits(-vt * inv) << 16);
            u1[r][c] = __builtin_bit_cast(float, packed);
            u2[r][c] = -vb * DOG_IC;
        }
        __syncthreads();
        #pragma unroll
        for (int p = 0; p < 4; p++) {
            int idx = p * 256 + tid;
            int c = idx >> 5, r = idx & 31;   // consecutive tid -> consecutive r
            roT[(din0 + c) * DOUT + dout0 + r] = __builtin_bit_cast(unsigned int, u1[r][c]);
            wnT[(din0 + c) * DOUT + dout0 + r] = (unsigned short)bf16bits(u2[r][c]);
        }
        return;
    }
    if (bid >= 1536) {
        // ---- convert role ---------------------------------------------------
        int e = ((bid - 1536) * 256 + tid) * 8;    // [0, 1179648)
        const float* src = (e < 1048576) ? (sw + e) : (bw + (e - 1048576));
        bf16* dst = (e < 1048576) ? (swb + e) : (bwb + (e - 1048576));
        float4 v0 = *(const float4*)src;
        float4 v1 = *(const float4*)(src + 4);
        short8 p;
        p[0] = __builtin_bit_cast(short, __float2bfloat16(v0.x));
        p[1] = __builtin_bit_cast(short, __float2bfloat16(v0.y));
        p[2] = __builtin_bit_cast(short, __float2bfloat16(v0.z));
        p[3] = __builtin_bit_cast(short, __float2bfloat16(v0.w));
        p[4] = __builtin_bit_cast(short, __float2bfloat16(v1.x));
        p[5] = __builtin_bit_cast(short, __float2bfloat16(v1.y));
        p[6] = __builtin_bit_cast(short, __float2bfloat16(v1.z));
        p[7] = __builtin_bit_cast(short, __float2bfloat16(v1.w));
        *(short8*)dst = p;
        return;
    }

    // ---- LN + basis role ----------------------------------------------------
    int wv = tid >> 6, lane = tid & 63;
    int row = bid * 4 + wv;              // b*1024 + t
    int batch = row >> 10, t = row & 1023;

    float x[4];
    #pragma unroll
    for (int j = 0; j < 4; j++) x[j] = X[(size_t)row * DIN + j * 64 + lane];
    float s = x[0] + x[1] + x[2] + x[3];
    float ss = x[0] * x[0] + x[1] * x[1] + x[2] * x[2] + x[3] * x[3];
    #pragma unroll
    for (int o = 1; o < 64; o <<= 1) {
        s  += __shfl_xor(s, o);
        ss += __shfl_xor(ss, o);
    }
    float mu = s * (1.0f / DIN);
    float rstd = rsqrtf(ss * (1.0f / DIN) - mu * mu + 1e-5f);

    float xn[4];
    #pragma unroll
    for (int j = 0; j < 4; j++) {
        int din = j * 64 + lane;
        xn[j] = (x[j] - mu) * rstd * w[din] + b[din];
    }

    if (batch == 2) {
        #pragma unroll
        for (int j = 0; j < 4; j++)
            Xn2[(size_t)t * DIN + j * 64 + lane] = xn[j];
    } else if (batch == 3) {
        #pragma unroll
        for (int j = 0; j < 4; j++) {
            float e = __builtin_amdgcn_exp2f(-xn[j] * LOG2E);
            float si = xn[j] * __builtin_amdgcn_rcpf(1.0f + e);
            Sm[(size_t)t * DIN + j * 64 + lane] = __float2bfloat16(si);
        }
    } else {
        int which = (batch == 0) ? 0 : (batch == 1) ? 1 : (batch == 4) ? 2 : 3;
        bool is_rbf = (batch == 0) || (batch == 4);
        #pragma unroll
        for (int j = 0; j < 4; j++) {
            float v = xn[j];
            float outv[NG];
            if (is_rbf) {
                #pragma unroll
                for (int g = 0; g < NG; g++) {
                    float d = (v - grid_rbf[g]) * INV_DENOM;
                    outv[g] = __builtin_amdgcn_exp2f(-d * d * LOG2E);
                }
            } else {
                float g[12];
                #pragma unroll
                for (int i = 0; i < 12; i++) g[i] = grid_bs[i];
                float ih = 1.0f / (g[1] - g[0]);
                float ihk[3] = {ih, ih * 0.5f, ih * (1.0f / 3.0f)};
                float bs_[11];
                #pragma unroll
                for (int i = 0; i < 11; i++)
                    bs_[i] = (v >= g[i] && v < g[i + 1]) ? 1.0f : 0.0f;
                #pragma unroll
                for (int k = 1; k <= 3; k++) {
                    float rk = ihk[k - 1];
                    #pragma unroll
                    for (int i = 0; i < 10; i++) {
                        if (i <= 10 - k) {
                            bs_[i] = (v - g[i]) * rk * bs_[i]
                                   + (g[i + k + 1] - v) * rk * bs_[i + 1];
                        }
                    }
                }
                #pragma unroll
                for (int gg = 0; gg < NG; gg++) outv[gg] = bs_[gg];
            }
            short8 pv;
            #pragma unroll
            for (int gg = 0; gg < NG; gg++)
                pv[gg] = __builtin_bit_cast(short, __float2bfloat16(outv[gg]));
            *(short8*)((short*)Amat + (size_t)(which * Tn + t) * KSP
                       + (size_t)(j * 64 + lane) * NG) = pv;
        }
    }
}

// ---------------- GEMM core: 128x128 tile, BK=32, 3-buf LDS, counted vmcnt ---
// 4 waves; each wave owns a 64x64 output quadrant (4x4 16x16 fragments).
// Per wave-K-step: 8 ds_read_b128 feed 16 MFMA. Loads issued 2 iters ahead;
// wait order: s_waitcnt vmcnt(4) (own tile landed) -> s_barrier (cross-wave
// publish) -> issue prefetch into just-freed buffer -> ds_read + MFMA.
template <int KS>
__device__ __forceinline__ void gemm128(const short* __restrict__ A,
                                        const short* __restrict__ Bw,
                                        int row0, int col0, int iters,
                                        int tid, char* smem, floatx4 acc[4][4]) {
    short* ldsA = (short*)smem;             // [3][128][32] = 24 KiB
    short* ldsB = (short*)(smem + 24576);   // [3][128][32] = 24 KiB
    int wv = tid >> 6, lane = tid & 63;
    int r16 = lane >> 2, cs = lane & 3;
    // staging: wave wv covers rows [wv*32, wv*32+32), two issues of 16 rows.
    // LDS dest is linear (wave base + lane*16B); source pre-swizzled so that
    // physical chunk p of row r holds global chunk p ^ ((r>>1)&3).
    int sr0 = wv * 32 + r16, sr1 = sr0 + 16;
    int cg0 = cs ^ ((sr0 >> 1) & 3);
    int cg1 = cs ^ ((sr1 >> 1) & 3);
    const short* gA0 = A  + (size_t)(row0 + sr0) * KS + cg0 * 8;
    const short* gA1 = A  + (size_t)(row0 + sr1) * KS + cg1 * 8;
    const short* gB0 = Bw + (size_t)(col0 + sr0) * KS + cg0 * 8;
    const short* gB1 = Bw + (size_t)(col0 + sr1) * KS + cg1 * 8;

    int m = lane & 15, q = lane >> 4;
    int wr = wv >> 1, wc = wv & 1;
    int oA[4], oB[4];
    #pragma unroll
    for (int i = 0; i < 4; i++) {
        int ra = wr * 64 + i * 16 + m;
        int rb = wc * 64 + i * 16 + m;
        oA[i] = ra * 32 + (q ^ ((ra >> 1) & 3)) * 8;
        oB[i] = rb * 32 + (q ^ ((rb >> 1) & 3)) * 8;
    }

    auto issue = [&](int buf, int kof) {
        short* dA = ldsA + buf * 4096 + wv * 1024;
        short* dB = ldsB + buf * 4096 + wv * 1024;
        __builtin_amdgcn_global_load_lds(
            (const __attribute__((address_space(1))) void*)(gA0 + kof),
            (__attribute__((address_space(3))) void*)dA, 16, 0, 0);
        __builtin_amdgcn_global_load_lds(
            (const __attribute__((address_space(1))) void*)(gA1 + kof),
            (__attribute__((address_space(3))) void*)(dA + 512), 16, 0, 0);
        __builtin_amdgcn_global_load_lds(
            (const __attribute__((address_space(1))) void*)(gB0 + kof),
            (__attribute__((address_space(3))) void*)dB, 16, 0, 0);
        __builtin_amdgcn_global_load_lds(
            (const __attribute__((address_space(1))) void*)(gB1 + kof),
            (__attribute__((address_space(3))) void*)(dB + 512), 16, 0, 0);
    };

    issue(0, 0);
    if (iters > 1) issue(1, 32);
    int cur = 0, pf = 2;
    for (int i = 0; i < iters; i++) {
        // own prefetched tile for iter i has landed when <=4 newer remain
        if (i + 1 < iters) {
            asm volatile("s_waitcnt vmcnt(4)" ::: "memory");
        } else {
            asm volatile("s_waitcnt vmcnt(0)" ::: "memory");
        }
        asm volatile("s_barrier" ::: "memory");
        if (i + 2 < iters) issue(pf, (i + 2) * 32);
        const short* bA = ldsA + cur * 4096;
        const short* bB = ldsB + cur * 4096;
        short8 a[4], b[4];
        #pragma unroll
        for (int r = 0; r < 4; r++) {
            a[r] = *(const short8*)(bA + oA[r]);
            b[r] = *(const short8*)(bB + oB[r]);
        }
        #pragma unroll
        for (int r = 0; r < 4; r++)
            #pragma unroll
            for (int c = 0; c < 4; c++)
                acc[r][c] = __builtin_amdgcn_mfma_f32_16x16x32_bf16(
                    a[r], b[c], acc[r][c], 0, 0, 0);
        cur = (cur == 2) ? 0 : cur + 1;
        pf  = (pf  == 2) ? 0 : pf + 1;
    }
}

// ================= K2: heterogeneous mega-kernel =============================
// [0,128):   spline GEMM 128x128, K=2048, direct f32 epilogue  (first: overlap)
// [128,160): base GEMM 128x128, K=256
// [160,672): DoG: block = 256 unique dout x 4 t (fills VALU while GEMM runs)
__global__ __launch_bounds__(256) void k2_kernel(const bf16* __restrict__ Amat,
                                                 const bf16* __restrict__ SWb,
                                                 const bf16* __restrict__ Sm,
                                                 const bf16* __restrict__ BWb,
                                                 const float* __restrict__ Xn2,
                                                 const unsigned int* __restrict__ roT,
                                                 const unsigned short* __restrict__ wnT,
                                                 float* __restrict__ out) {
    __shared__ alignas(16) char smem[49152];
    int bid = blockIdx.x, tid = threadIdx.x;

    if (bid < 128) {
        // ---- spline GEMM role: 128x128, K=2048, f32 direct -----------------
        int mt = bid >> 2, nt = bid & 3;        // 32 x 4
        int row0 = mt * 128, col0 = nt * 128;
        floatx4 acc[4][4];
        #pragma unroll
        for (int r = 0; r < 4; r++)
            #pragma unroll
            for (int c = 0; c < 4; c++) acc[r][c] = (floatx4)(0.0f);
        gemm128<KSP>((const short*)Amat, (const short*)SWb,
                     row0, col0, 64, tid, smem, acc);
        int which = row0 >> 10;                  // block never crosses a 1024-row seam
        int batch = (which == 0) ? 0 : (which == 1) ? 1 : (which == 2) ? 4 : 5;
        int t0 = row0 & 1023;
        int wv = tid >> 6, lane = tid & 63;
        int m = lane & 15, q = lane >> 4;
        int wr = wv >> 1, wc = wv & 1;
        #pragma unroll
        for (int r = 0; r < 4; r++)
            #pragma unroll
            for (int c = 0; c < 4; c++)
                #pragma unroll
                for (int rr = 0; rr < 4; rr++) {
                    int t = t0 + wr * 64 + r * 16 + q * 4 + rr;
                    int col = col0 + wc * 64 + c * 16 + m;
                    out[((size_t)batch * Tn + t) * DOUT + col] = acc[r][c][rr];
                }
    } else if (bid < 160) {
        // ---- base GEMM role: 128x128, K=256 --------------------------------
        int idx = bid - 128;
        int mt = idx >> 2, nt = idx & 3;        // 8 x 4
        int row0 = mt * 128, col0 = nt * 128;
        floatx4 acc[4][4];
        #pragma unroll
        for (int r = 0; r < 4; r++)
            #pragma unroll
            for (int c = 0; c < 4; c++) acc[r][c] = (floatx4)(0.0f);
        gemm128<DIN>((const short*)Sm, (const short*)BWb,
                     row0, col0, 8, tid, smem, acc);
        int wv = tid >> 6, lane = tid & 63;
        int m = lane & 15, q = lane >> 4;
        int wr = wv >> 1, wc = wv & 1;
        #pragma unroll
        for (int r = 0; r < 4; r++)
            #pragma unroll
            for (int c = 0; c < 4; c++)
                #pragma unroll
                for (int rr = 0; rr < 4; rr++) {
                    int row = row0 + wr * 64 + r * 16 + q * 4 + rr;
                    int col = col0 + wc * 64 + c * 16 + m;
                    out[((size_t)3 * Tn + row) * DOUT + col] = acc[r][c][rr];
                }
    } else {
        // ---- DoG role: 256 dout x 4 t --------------------------------------
        int db = bid - 160;
        int dt = db & 1, t0 = (db >> 1) * 4;
        float* xs_ = (float*)smem;          // [4][256] = 4 KiB
        *(float4*)&xs_[tid * 4] = *(const float4*)&Xn2[(size_t)t0 * DIN + tid * 4];
        __syncthreads();

        int dout = dt * 256 + tid;
        float acc[4] = {0.f, 0.f, 0.f, 0.f};
        const unsigned int*   rop = roT + dout;
        const unsigned short* wnp = wnT + dout;

        for (int d = 0; d < DIN; d += 8) {
            unsigned int ro[8]; unsigned short wn[8];
            #pragma unroll
            for (int k = 0; k < 8; k++) {
                ro[k] = rop[(d + k) * DOUT];
                wn[k] = wnp[(d + k) * DOUT];
            }
            #pragma unroll
            for (int g = 0; g < 2; g++) {
                float4 xv[4];
                #pragma unroll
                for (int j = 0; j < 4; j++)
                    xv[j] = *(const float4*)&xs_[j * DIN + d + g * 4];  // broadcast
                #pragma unroll
                for (int k = 0; k < 4; k++) {
                    int kk = g * 4 + k;
                    float r = frombits(ro[kk] << 16);
                    float o = frombits(ro[kk] & 0xFFFF0000u);
                    float w = frombits(((unsigned int)wn[kk]) << 16);
                    #pragma unroll
                    for (int j = 0; j < 4; j++) {
                        float xval = ((const float*)&xv[j])[k];
                        float z = fmaf(xval, r, o);
                        float e = __builtin_amdgcn_exp2f(-(z * z));
                        acc[j] = fmaf(z * e, w, acc[j]);
                    }
                }
            }
        }
        size_t base = (size_t)2 * Tn * DOUT + (size_t)t0 * DOUT + dout;
        #pragma unroll
        for (int j = 0; j < 4; j++) out[base + (size_t)j * DOUT] = acc[j];
    }
}

extern "C" void kernel_launch(void* const* d_in, const int* in_sizes, int n_in,
                              void* d_out, int out_size, void* d_ws, size_t ws_size,
                              hipStream_t stream) {
    const float* X        = (const float*)d_in[0];
    const float* ln_w     = (const float*)d_in[1];
    const float* ln_b     = (const float*)d_in[2];
    const float* base_w   = (const float*)d_in[3];
    const float* spline_w = (const float*)d_in[4];
    const float* scale    = (const float*)d_in[5];
    const float* transl   = (const float*)d_in[6];
    const float* grid_rbf = (const float*)d_in[7];
    const float* grid_bs  = (const float*)d_in[8];
    float* out = (float*)d_out;

    char* ws = (char*)d_ws;
    bf16*  Amat = (bf16*)ws;                                   // 16 MiB   [4096][2048]
    bf16*  SWb  = (bf16*)(ws + 16777216);                      // 2 MiB    [512][2048]
    bf16*  BWb  = (bf16*)(ws + 18874368);                      // 0.25 MiB [512][256]
    bf16*  Sm   = (bf16*)(ws + 19136512);                      // 0.5 MiB  [1024][256]
    float* Xn2  = (float*)(ws + 19660800);                     // 1 MiB    [1024][256]
    unsigned int*   roT = (unsigned int*)(ws + 20709376);      // 0.5 MiB  [256][512]
    unsigned short* wnT = (unsigned short*)(ws + 21233664);    // 0.25 MiB [256][512]

    k1_kernel<<<2240, 256, 0, stream>>>(X, ln_w, ln_b, grid_rbf, grid_bs,
                                        spline_w, base_w, scale, transl,
                                        Amat, Sm, Xn2, SWb, BWb, roT, wnT);
    k2_kernel<<<672, 256, 0, stream>>>(Amat, SWb, Sm, BWb, Xn2, roT, wnT, out);
}

// Round 3
// 126.427 us; speedup vs baseline: 1.0835x; 1.0146x over previous
//
#include <hip/hip_runtime.h>
#include <hip/hip_bf16.h>

// FC_KANLayer: B=6, T=1024, D_IN=256, D_OUT=512, NUM_GRIDS=8
// FUNC_LIST = [rbf, bs, dog, base, rbf, bs]
// f32 in/out; GEMMs via bf16 MFMA.
// R15 = R14 + (a) DoG: zero LDS (broadcast x loads), 8t/thread, packed
// [DIN/8][DOUT][8] params (3 vector loads per d-block); (b) spline GEMM
// 64x128 tiles -> 256 blocks (all CUs), 3-buf counted vmcnt(3); (c) setprio
// around MFMA cluster (DoG waves give role diversity).

typedef short short8 __attribute__((ext_vector_type(8)));
typedef float floatx4 __attribute__((ext_vector_type(4)));

using bf16 = __hip_bfloat16;

#define LOG2E 1.44269504088896340736f
// c = sqrt(0.5*log2(e)); exp(-0.5 x^2) = exp2(-(c x)^2)
#define DOG_C  0.84932180028801904f
#define DOG_IC 1.17741002251547466f   // 1/c

constexpr int Tn   = 1024;
constexpr int DIN  = 256;
constexpr int DOUT = 512;
constexpr int NG   = 8;
constexpr int KSP  = DIN * NG;            // 2048
constexpr float INV_DENOM = 7.0f / 3.0f;  // 1/DENOM, DENOM = 3/7

__device__ __forceinline__ unsigned int bf16bits(float v) {
    return (unsigned int)__builtin_bit_cast(unsigned short, __float2bfloat16(v));
}
__device__ __forceinline__ float frombits(unsigned int u) {
    return __builtin_bit_cast(float, u);
}

// ================= K1 ========================================================
// [0,1536): LN+basis wave-per-row | [1536,2112): f32->bf16 convert (x8 vec)
// [2112,2176): dog-param pack into [DIN/8][DOUT][8] (pre-scaled by DOG_C)
__global__ __launch_bounds__(256) void k1_kernel(
        const float* __restrict__ X,
        const float* __restrict__ w,
        const float* __restrict__ b,
        const float* __restrict__ grid_rbf,
        const float* __restrict__ grid_bs,
        const float* __restrict__ sw,
        const float* __restrict__ bw,
        const float* __restrict__ sc,
        const float* __restrict__ tr,
        bf16* __restrict__ Amat,            // [4096][2048]
        bf16* __restrict__ Sm,              // [1024][256]
        float* __restrict__ Xn2,            // [1024][256]
        bf16* __restrict__ swb,             // [512][2048]
        bf16* __restrict__ bwb,             // [512][256]
        unsigned int* __restrict__ roP,     // [32][512][8] packed bf16 (c/s, -c*t/s)
        unsigned short* __restrict__ wnP) { // [32][512][8] bf16 (-bw/c)
    int tid = threadIdx.x, bid = blockIdx.x;

    if (bid >= 2112) {
        // ---- pack role: one thread per (dblk, dout) ------------------------
        int task = (bid - 2112) * 256 + tid;     // [0, 16384)
        int dout = task & 511, dblk = task >> 9; // dblk in [0,32)
        int base = dout * DIN + dblk * 8;
        float4 s0 = *(const float4*)&sc[base];
        float4 s1 = *(const float4*)&sc[base + 4];
        float4 t0v = *(const float4*)&tr[base];
        float4 t1v = *(const float4*)&tr[base + 4];
        float4 b0v = *(const float4*)&bw[base];
        float4 b1v = *(const float4*)&bw[base + 4];
        float vs[8] = {s0.x, s0.y, s0.z, s0.w, s1.x, s1.y, s1.z, s1.w};
        float vt[8] = {t0v.x, t0v.y, t0v.z, t0v.w, t1v.x, t1v.y, t1v.z, t1v.w};
        float vb[8] = {b0v.x, b0v.y, b0v.z, b0v.w, b1v.x, b1v.y, b1v.z, b1v.w};
        unsigned int ro_[8];
        unsigned short wn_[8];
        #pragma unroll
        for (int k = 0; k < 8; k++) {
            float inv = DOG_C / vs[k];
            ro_[k] = bf16bits(inv) | (bf16bits(-vt[k] * inv) << 16);
            wn_[k] = (unsigned short)bf16bits(-vb[k] * DOG_IC);
        }
        size_t obase = ((size_t)dblk * 512 + dout) * 8;
        uint4 r0; r0.x = ro_[0]; r0.y = ro_[1]; r0.z = ro_[2]; r0.w = ro_[3];
        uint4 r1; r1.x = ro_[4]; r1.y = ro_[5]; r1.z = ro_[6]; r1.w = ro_[7];
        *(uint4*)&roP[obase]     = r0;
        *(uint4*)&roP[obase + 4] = r1;
        uint4 wv_;
        wv_.x = (unsigned int)wn_[0] | ((unsigned int)wn_[1] << 16);
        wv_.y = (unsigned int)wn_[2] | ((unsigned int)wn_[3] << 16);
        wv_.z = (unsigned int)wn_[4] | ((unsigned int)wn_[5] << 16);
        wv_.w = (unsigned int)wn_[6] | ((unsigned int)wn_[7] << 16);
        *(uint4*)&wnP[obase] = wv_;
        return;
    }
    if (bid >= 1536) {
        // ---- convert role ---------------------------------------------------
        int e = ((bid - 1536) * 256 + tid) * 8;    // [0, 1179648)
        const float* src = (e < 1048576) ? (sw + e) : (bw + (e - 1048576));
        bf16* dst = (e < 1048576) ? (swb + e) : (bwb + (e - 1048576));
        float4 v0 = *(const float4*)src;
        float4 v1 = *(const float4*)(src + 4);
        short8 p;
        p[0] = __builtin_bit_cast(short, __float2bfloat16(v0.x));
        p[1] = __builtin_bit_cast(short, __float2bfloat16(v0.y));
        p[2] = __builtin_bit_cast(short, __float2bfloat16(v0.z));
        p[3] = __builtin_bit_cast(short, __float2bfloat16(v0.w));
        p[4] = __builtin_bit_cast(short, __float2bfloat16(v1.x));
        p[5] = __builtin_bit_cast(short, __float2bfloat16(v1.y));
        p[6] = __builtin_bit_cast(short, __float2bfloat16(v1.z));
        p[7] = __builtin_bit_cast(short, __float2bfloat16(v1.w));
        *(short8*)dst = p;
        return;
    }

    // ---- LN + basis role ----------------------------------------------------
    int wv = tid >> 6, lane = tid & 63;
    int row = bid * 4 + wv;              // b*1024 + t
    int batch = row >> 10, t = row & 1023;

    float x[4];
    #pragma unroll
    for (int j = 0; j < 4; j++) x[j] = X[(size_t)row * DIN + j * 64 + lane];
    float s = x[0] + x[1] + x[2] + x[3];
    float ss = x[0] * x[0] + x[1] * x[1] + x[2] * x[2] + x[3] * x[3];
    #pragma unroll
    for (int o = 1; o < 64; o <<= 1) {
        s  += __shfl_xor(s, o);
        ss += __shfl_xor(ss, o);
    }
    float mu = s * (1.0f / DIN);
    float rstd = rsqrtf(ss * (1.0f / DIN) - mu * mu + 1e-5f);

    float xn[4];
    #pragma unroll
    for (int j = 0; j < 4; j++) {
        int din = j * 64 + lane;
        xn[j] = (x[j] - mu) * rstd * w[din] + b[din];
    }

    if (batch == 2) {
        #pragma unroll
        for (int j = 0; j < 4; j++)
            Xn2[(size_t)t * DIN + j * 64 + lane] = xn[j];
    } else if (batch == 3) {
        #pragma unroll
        for (int j = 0; j < 4; j++) {
            float e = __builtin_amdgcn_exp2f(-xn[j] * LOG2E);
            float si = xn[j] * __builtin_amdgcn_rcpf(1.0f + e);
            Sm[(size_t)t * DIN + j * 64 + lane] = __float2bfloat16(si);
        }
    } else {
        int which = (batch == 0) ? 0 : (batch == 1) ? 1 : (batch == 4) ? 2 : 3;
        bool is_rbf = (batch == 0) || (batch == 4);
        #pragma unroll
        for (int j = 0; j < 4; j++) {
            float v = xn[j];
            float outv[NG];
            if (is_rbf) {
                #pragma unroll
                for (int g = 0; g < NG; g++) {
                    float d = (v - grid_rbf[g]) * INV_DENOM;
                    outv[g] = __builtin_amdgcn_exp2f(-d * d * LOG2E);
                }
            } else {
                float g[12];
                #pragma unroll
                for (int i = 0; i < 12; i++) g[i] = grid_bs[i];
                float ih = 1.0f / (g[1] - g[0]);
                float ihk[3] = {ih, ih * 0.5f, ih * (1.0f / 3.0f)};
                float bs_[11];
                #pragma unroll
                for (int i = 0; i < 11; i++)
                    bs_[i] = (v >= g[i] && v < g[i + 1]) ? 1.0f : 0.0f;
                #pragma unroll
                for (int k = 1; k <= 3; k++) {
                    float rk = ihk[k - 1];
                    #pragma unroll
                    for (int i = 0; i < 10; i++) {
                        if (i <= 10 - k) {
                            bs_[i] = (v - g[i]) * rk * bs_[i]
                                   + (g[i + k + 1] - v) * rk * bs_[i + 1];
                        }
                    }
                }
                #pragma unroll
                for (int gg = 0; gg < NG; gg++) outv[gg] = bs_[gg];
            }
            short8 pv;
            #pragma unroll
            for (int gg = 0; gg < NG; gg++)
                pv[gg] = __builtin_bit_cast(short, __float2bfloat16(outv[gg]));
            *(short8*)((short*)Amat + (size_t)(which * Tn + t) * KSP
                       + (size_t)(j * 64 + lane) * NG) = pv;
        }
    }
}

// ---------------- GEMM core: 64x128 tile, BK=32, 3-buf LDS, counted vmcnt ----
// 4 waves (2 row x 2 col), each owns a 32x64 quadrant (2x4 16x16 frags).
// Per wave-K-step: 6 ds_read_b128 feed 8 MFMA; 3 global_load_lds per wave.
template <int KS>
__device__ __forceinline__ void gemm_64x128(const short* __restrict__ A,
                                            const short* __restrict__ Bw,
                                            int row0, int col0, int iters,
                                            int tid, char* smem, floatx4 acc[2][4]) {
    short* ldsA = (short*)smem;             // [3][64][32]  = 12 KiB
    short* ldsB = (short*)(smem + 12288);   // [3][128][32] = 24 KiB
    int wv = tid >> 6, lane = tid & 63;
    int r16 = lane >> 2, cs = lane & 3;
    // A staging: wave wv rows [wv*16, wv*16+16) -> 1 issue
    int srA = wv * 16 + r16;
    int cgA = cs ^ ((srA >> 1) & 3);
    const short* gA = A + (size_t)(row0 + srA) * KS + cgA * 8;
    // B staging: wave wv rows [wv*32, wv*32+32) -> 2 issues
    int srB0 = wv * 32 + r16, srB1 = srB0 + 16;
    int cgB0 = cs ^ ((srB0 >> 1) & 3);
    int cgB1 = cs ^ ((srB1 >> 1) & 3);
    const short* gB0 = Bw + (size_t)(col0 + srB0) * KS + cgB0 * 8;
    const short* gB1 = Bw + (size_t)(col0 + srB1) * KS + cgB1 * 8;

    int m = lane & 15, q = lane >> 4;
    int wr = wv >> 1, wc = wv & 1;
    int oA[2], oB[4];
    #pragma unroll
    for (int i = 0; i < 2; i++) {
        int ra = wr * 32 + i * 16 + m;
        oA[i] = ra * 32 + (q ^ ((ra >> 1) & 3)) * 8;
    }
    #pragma unroll
    for (int i = 0; i < 4; i++) {
        int rb = wc * 64 + i * 16 + m;
        oB[i] = rb * 32 + (q ^ ((rb >> 1) & 3)) * 8;
    }

    auto issue = [&](int buf, int kof) {
        short* dA = ldsA + buf * 2048 + wv * 512;
        short* dB = ldsB + buf * 4096 + wv * 1024;
        __builtin_amdgcn_global_load_lds(
            (const __attribute__((address_space(1))) void*)(gA + kof),
            (__attribute__((address_space(3))) void*)dA, 16, 0, 0);
        __builtin_amdgcn_global_load_lds(
            (const __attribute__((address_space(1))) void*)(gB0 + kof),
            (__attribute__((address_space(3))) void*)dB, 16, 0, 0);
        __builtin_amdgcn_global_load_lds(
            (const __attribute__((address_space(1))) void*)(gB1 + kof),
            (__attribute__((address_space(3))) void*)(dB + 512), 16, 0, 0);
    };

    issue(0, 0);
    if (iters > 1) issue(1, 32);
    int cur = 0, pf = 2;
    for (int i = 0; i < iters; i++) {
        // own 3 loads for iter i done when <=3 newer remain in the queue
        if (i + 1 < iters) {
            asm volatile("s_waitcnt vmcnt(3)" ::: "memory");
        } else {
            asm volatile("s_waitcnt vmcnt(0)" ::: "memory");
        }
        asm volatile("s_barrier" ::: "memory");
        if (i + 2 < iters) issue(pf, (i + 2) * 32);
        const short* bA = ldsA + cur * 2048;
        const short* bB = ldsB + cur * 4096;
        short8 a[2], b[4];
        #pragma unroll
        for (int r = 0; r < 2; r++) a[r] = *(const short8*)(bA + oA[r]);
        #pragma unroll
        for (int c = 0; c < 4; c++) b[c] = *(const short8*)(bB + oB[c]);
        __builtin_amdgcn_s_setprio(1);
        #pragma unroll
        for (int r = 0; r < 2; r++)
            #pragma unroll
            for (int c = 0; c < 4; c++)
                acc[r][c] = __builtin_amdgcn_mfma_f32_16x16x32_bf16(
                    a[r], b[c], acc[r][c], 0, 0, 0);
        __builtin_amdgcn_s_setprio(0);
        cur = (cur == 2) ? 0 : cur + 1;
        pf  = (pf  == 2) ? 0 : pf + 1;
    }
}

// ================= K2: heterogeneous mega-kernel =============================
// [0,256):   spline GEMM 64x128, K=2048 (all CUs, first in dispatch order)
// [256,320): base GEMM 64x128, K=256
// [320,576): DoG: 256 dout x 8 t, zero LDS, packed params
__global__ __launch_bounds__(256) void k2_kernel(const bf16* __restrict__ Amat,
                                                 const bf16* __restrict__ SWb,
                                                 const bf16* __restrict__ Sm,
                                                 const bf16* __restrict__ BWb,
                                                 const float* __restrict__ Xn2,
                                                 const unsigned int* __restrict__ roP,
                                                 const unsigned short* __restrict__ wnP,
                                                 float* __restrict__ out) {
    __shared__ alignas(16) char smem[36864];
    int bid = blockIdx.x, tid = threadIdx.x;

    if (bid < 256) {
        // ---- spline GEMM role: 64x128, K=2048, f32 direct ------------------
        int mt = bid >> 2, nt = bid & 3;        // 64 x 4
        int row0 = mt * 64, col0 = nt * 128;
        floatx4 acc[2][4];
        #pragma unroll
        for (int r = 0; r < 2; r++)
            #pragma unroll
            for (int c = 0; c < 4; c++) acc[r][c] = (floatx4)(0.0f);
        gemm_64x128<KSP>((const short*)Amat, (const short*)SWb,
                         row0, col0, 64, tid, smem, acc);
        int which = row0 >> 10;                  // 64-row block within one batch
        int batch = (which == 0) ? 0 : (which == 1) ? 1 : (which == 2) ? 4 : 5;
        int t0 = row0 & 1023;
        int wv = tid >> 6, lane = tid & 63;
        int m = lane & 15, q = lane >> 4;
        int wr = wv >> 1, wc = wv & 1;
        #pragma unroll
        for (int r = 0; r < 2; r++)
            #pragma unroll
            for (int c = 0; c < 4; c++)
                #pragma unroll
                for (int rr = 0; rr < 4; rr++) {
                    int t = t0 + wr * 32 + r * 16 + q * 4 + rr;
                    int col = col0 + wc * 64 + c * 16 + m;
                    out[((size_t)batch * Tn + t) * DOUT + col] = acc[r][c][rr];
                }
    } else if (bid < 320) {
        // ---- base GEMM role: 64x128, K=256 ---------------------------------
        int idx = bid - 256;
        int mt = idx >> 2, nt = idx & 3;        // 16 x 4
        int row0 = mt * 64, col0 = nt * 128;
        floatx4 acc[2][4];
        #pragma unroll
        for (int r = 0; r < 2; r++)
            #pragma unroll
            for (int c = 0; c < 4; c++) acc[r][c] = (floatx4)(0.0f);
        gemm_64x128<DIN>((const short*)Sm, (const short*)BWb,
                         row0, col0, 8, tid, smem, acc);
        int wv = tid >> 6, lane = tid & 63;
        int m = lane & 15, q = lane >> 4;
        int wr = wv >> 1, wc = wv & 1;
        #pragma unroll
        for (int r = 0; r < 2; r++)
            #pragma unroll
            for (int c = 0; c < 4; c++)
                #pragma unroll
                for (int rr = 0; rr < 4; rr++) {
                    int row = row0 + wr * 32 + r * 16 + q * 4 + rr;
                    int col = col0 + wc * 64 + c * 16 + m;
                    out[((size_t)3 * Tn + row) * DOUT + col] = acc[r][c][rr];
                }
    } else {
        // ---- DoG role: 256 dout x 8 t, zero LDS ----------------------------
        int db = bid - 320;
        int dt = db & 1, t0 = (db >> 1) * 8;     // t0 in {0,8,...,1016}
        int dout = dt * 256 + tid;

        const unsigned int*   rop = roP + (size_t)dout * 8;
        const unsigned short* wnp = wnP + (size_t)dout * 8;
        const float* xrow[8];
        #pragma unroll
        for (int j = 0; j < 8; j++) xrow[j] = Xn2 + (size_t)(t0 + j) * DIN;

        float acc[8] = {0.f, 0.f, 0.f, 0.f, 0.f, 0.f, 0.f, 0.f};

        for (int db8 = 0; db8 < 32; db8++) {
            int d = db8 * 8;
            uint4 ra = *(const uint4*)rop;
            uint4 rb = *(const uint4*)(rop + 4);
            uint4 wq = *(const uint4*)wnp;
            rop += 4096;   // 512*8 uints per d-block
            wnp += 4096;   // 512*8 ushorts per d-block
            unsigned int roarr[8] = {ra.x, ra.y, ra.z, ra.w,
                                     rb.x, rb.y, rb.z, rb.w};
            unsigned int wword[4] = {wq.x, wq.y, wq.z, wq.w};
            #pragma unroll
            for (int g = 0; g < 2; g++) {
                float4 xj[8];
                #pragma unroll
                for (int j = 0; j < 8; j++)
                    xj[j] = *(const float4*)&xrow[j][d + g * 4];   // broadcast
                #pragma unroll
                for (int kq = 0; kq < 4; kq++) {
                    int k = g * 4 + kq;
                    unsigned int rw = roarr[k];
                    float r = frombits(rw << 16);
                    float o = frombits(rw & 0xFFFF0000u);
                    unsigned int ww = wword[k >> 1];
                    float w = (k & 1) ? frombits(ww & 0xFFFF0000u)
                                      : frombits(ww << 16);
                    #pragma unroll
                    for (int j = 0; j < 8; j++) {
                        float xval = ((const float*)&xj[j])[kq];
                        float z = fmaf(xval, r, o);
                        float e = __builtin_amdgcn_exp2f(-(z * z));
                        acc[j] = fmaf(z * e, w, acc[j]);
                    }
                }
            }
        }
        size_t base = (size_t)2 * Tn * DOUT + (size_t)t0 * DOUT + dout;
        #pragma unroll
        for (int j = 0; j < 8; j++) out[base + (size_t)j * DOUT] = acc[j];
    }
}

extern "C" void kernel_launch(void* const* d_in, const int* in_sizes, int n_in,
                              void* d_out, int out_size, void* d_ws, size_t ws_size,
                              hipStream_t stream) {
    const float* X        = (const float*)d_in[0];
    const float* ln_w     = (const float*)d_in[1];
    const float* ln_b     = (const float*)d_in[2];
    const float* base_w   = (const float*)d_in[3];
    const float* spline_w = (const float*)d_in[4];
    const float* scale    = (const float*)d_in[5];
    const float* transl   = (const float*)d_in[6];
    const float* grid_rbf = (const float*)d_in[7];
    const float* grid_bs  = (const float*)d_in[8];
    float* out = (float*)d_out;

    char* ws = (char*)d_ws;
    bf16*  Amat = (bf16*)ws;                                   // 16 MiB   [4096][2048]
    bf16*  SWb  = (bf16*)(ws + 16777216);                      // 2 MiB    [512][2048]
    bf16*  BWb  = (bf16*)(ws + 18874368);                      // 0.25 MiB [512][256]
    bf16*  Sm   = (bf16*)(ws + 19136512);                      // 0.5 MiB  [1024][256]
    float* Xn2  = (float*)(ws + 19660800);                     // 1 MiB    [1024][256]
    unsigned int*   roP = (unsigned int*)(ws + 20709376);      // 0.5 MiB  [32][512][8]
    unsigned short* wnP = (unsigned short*)(ws + 21233664);    // 0.25 MiB [32][512][8]

    k1_kernel<<<2176, 256, 0, stream>>>(X, ln_w, ln_b, grid_rbf, grid_bs,
                                        spline_w, base_w, scale, transl,
                                        Amat, Sm, Xn2, SWb, BWb, roP, wnP);
    k2_kernel<<<576, 256, 0, stream>>>(Amat, SWb, Sm, BWb, Xn2, roP, wnP, out);
}